// Round 17
// baseline (183.961 us; speedup 1.0000x reference)
//
#include <hip/hip_runtime.h>
#include <hip/hip_bf16.h>
#include <stdint.h>

// Attention_37031208026285: x[4,2048,1024] fp32, seq_lens[4] i32, wq/wk/wv/wo[1024,1024] fp32
// out = softmax_masked((rope(x@wq.T)) @ rope(x@wk.T)^T / 8) @ (x@wv.T) @ wo.T   (fp32 out)

typedef __attribute__((ext_vector_type(8))) short s8v;
typedef __attribute__((ext_vector_type(2))) float f2v;
typedef __attribute__((ext_vector_type(4))) float f4v;
typedef __attribute__((ext_vector_type(16))) float f16v;

#define GLL16(gsrc, ldst) __builtin_amdgcn_global_load_lds(              \
    (const __attribute__((address_space(1))) void*)(gsrc),               \
    (__attribute__((address_space(3))) void*)(ldst), 16, 0, 0)

__device__ __forceinline__ short f2bf(float f) {
  union { float f; unsigned i; } v; v.f = f;
  unsigned r = v.i + 0x7fffu + ((v.i >> 16) & 1u);
  return (short)(r >> 16);
}
__device__ __forceinline__ unsigned cvtpk(float a, float b) {
  unsigned r;
  asm("v_cvt_pk_bf16_f32 %0, %1, %2" : "=v"(r) : "v"(a), "v"(b));
  return r;
}
__device__ __forceinline__ void plswap(unsigned& x, unsigned& y) {
  asm volatile("v_permlane32_swap_b32 %0, %1" : "+v"(x), "+v"(y));
}

// ---------- K0: merged prep: rope tables + all fp32->bf16 conversions (1 launch) ----------
__global__ __launch_bounds__(256) void k_prep(
    const float* __restrict__ x,
    const float* __restrict__ wq, const float* __restrict__ wk,
    const float* __restrict__ wv, const float* __restrict__ wo,
    float* __restrict__ ct, float* __restrict__ st,
    short* __restrict__ xb, short* __restrict__ wqkv, short* __restrict__ wob)
{
  int id = blockIdx.x * 256 + threadIdx.x;
  if (id < 65536) {
    const int pos = id >> 5, i = id & 31;
    float inv = exp2f(-13.287712379549449f * ((float)i / 32.0f)); // 10000^(-i/32)
    float a = (float)pos * inv;
    float s, c;
    sincosf(a, &s, &c);
    ct[id] = c; st[id] = s;
    return;
  }
  id -= 65536;
  if (id < 2097152) {
    float4 v = ((const float4*)x)[id];
    short4 o;
    o.x = f2bf(v.x); o.y = f2bf(v.y); o.z = f2bf(v.z); o.w = f2bf(v.w);
    ((short4*)xb)[id] = o;
    return;
  }
  id -= 2097152;
  const int sel = id >> 18;            // 0=wq 1=wk 2=wv 3=wo
  const int off = id & 262143;
  const float* src = (sel == 0) ? wq : (sel == 1) ? wk : (sel == 2) ? wv : wo;
  short* dst = (sel < 3) ? (wqkv + (size_t)sel * 1048576) : wob;
  float4 v = ((const float4*)src)[off];
  short4 o;
  o.x = f2bf(v.x); o.y = f2bf(v.y); o.z = f2bf(v.z); o.w = f2bf(v.w);
  ((short4*)dst)[off] = o;
}

// ---------- K2: QKV GEMM 128x128 tile, 4 waves, dbuf + counted vmcnt, T2 swizzle ----------
// Intra-XCD L2 supertiling (8 supertiles of 8m x 3n, 2.75 MB footprint).
// Direct-store epilogue: RoPE for q/k (q pre-scaled by 0.125*log2e), v written transposed.
__global__ __launch_bounds__(256, 2) void k_gemm_qkv(
    const short* __restrict__ xb, const short* __restrict__ wb,
    const float* __restrict__ ct, const float* __restrict__ st,
    short* __restrict__ qb, short* __restrict__ kb, short* __restrict__ vt)
{
  __shared__ short As[2][128 * 64];
  __shared__ short Bs[2][128 * 64];
  const int bid = blockIdx.x;
  const int j = bid >> 3;                     // 0..191 within XCD
  const int stile = j / 24;                   // 8 supertiles
  const int r0 = j - stile * 24;              // 0..23 = 8 m x 3 n
  const int row_m = (stile * 8 + (r0 & 7)) * 128;
  const int row_n = ((bid & 7) * 3 + (r0 >> 3)) * 128;
  const int tid = threadIdx.x;
  const int lane = tid & 63, w = tid >> 6;
  const int g = lane >> 4, lq = lane & 15;
  const int wm = (w >> 1) * 64, wn = (w & 1) * 64;
  const int srow = tid >> 3;                       // 0..31
  const int schunk = (lane & 7) ^ ((lane >> 3) & 7);

  f4v acc[4][4];
#pragma unroll
  for (int i = 0; i < 4; i++)
#pragma unroll
    for (int jj = 0; jj < 4; jj++) acc[i][jj] = f4v{0.f, 0.f, 0.f, 0.f};

  auto stage = [&](int kt, int s) {
#pragma unroll
    for (int jj = 0; jj < 4; jj++)
      GLL16(xb + (size_t)(row_m + jj * 32 + srow) * 1024 + kt + schunk * 8,
            &As[s][jj * 2048 + w * 512]);
#pragma unroll
    for (int jj = 0; jj < 4; jj++)
      GLL16(wb + (size_t)(row_n + jj * 32 + srow) * 1024 + kt + schunk * 8,
            &Bs[s][jj * 2048 + w * 512]);
  };

  stage(0, 0);
  stage(64, 1);
  asm volatile("s_waitcnt vmcnt(8)" ::: "memory");
  __builtin_amdgcn_sched_barrier(0);
  asm volatile("s_barrier" ::: "memory");

  for (int t = 0; t < 16; t++) {
    const int s = t & 1;
    const short* Ac = &As[s][0];
    const short* Bc = &Bs[s][0];
#pragma unroll
    for (int kk = 0; kk < 2; kk++) {
      s8v a[4], b[4];
#pragma unroll
      for (int mi = 0; mi < 4; mi++) {
        const int r_ = wm + mi * 16 + lq;
        a[mi] = *(const s8v*)&Ac[r_ * 64 + (((kk * 4 + g) ^ (lq & 7)) * 8)];
      }
#pragma unroll
      for (int ni = 0; ni < 4; ni++) {
        const int r_ = wn + ni * 16 + lq;
        b[ni] = *(const s8v*)&Bc[r_ * 64 + (((kk * 4 + g) ^ (lq & 7)) * 8)];
      }
      __builtin_amdgcn_s_setprio(1);
#pragma unroll
      for (int mi = 0; mi < 4; mi++)
#pragma unroll
        for (int ni = 0; ni < 4; ni++)
          acc[mi][ni] = __builtin_amdgcn_mfma_f32_16x16x32_bf16(a[mi], b[ni], acc[mi][ni], 0, 0, 0);
      __builtin_amdgcn_s_setprio(0);
    }
    if (t < 15) {
      asm volatile("s_waitcnt lgkmcnt(0)" ::: "memory");
      asm volatile("s_barrier" ::: "memory");             // all waves done reading slot s
      if (t < 14) {
        stage((t + 2) * 64, s);
        asm volatile("s_waitcnt vmcnt(8)" ::: "memory");  // t+1 landed; t+2 in flight
      } else {
        asm volatile("s_waitcnt vmcnt(0)" ::: "memory");
      }
      __builtin_amdgcn_sched_barrier(0);
      asm volatile("s_barrier" ::: "memory");             // slot s^1 ready
    }
  }

  // Epilogue. C element (t,o): t = row_m+wm+mi*16+g*4+r, o = row_n+wn+ni*16+lq
  const int sel = row_n >> 10;   // 0=q 1=k 2=v (128-tiles don't straddle)
  if (sel < 2) {
    const float qsc = (sel == 0) ? 0.18033688011112042f : 1.0f;  // fold 1/8*log2e into q
    short* __restrict__ dst = (sel == 0) ? qb : kb;
#pragma unroll
    for (int mi = 0; mi < 4; mi++) {
#pragma unroll
      for (int ni = 0; ni < 4; ni++) {
        const int o = row_n + wn + ni * 16 + lq;
        const int oin = o & 1023, h = oin >> 6, d = oin & 63;
#pragma unroll
        for (int r = 0; r < 4; r++) {
          const int tt = row_m + wm + mi * 16 + g * 4 + r;
          const int b_ = tt >> 11, s_ = tt & 2047;
          float v = acc[mi][ni][r];
          float p = __shfl_xor(v, 1);          // pair partner (o^1), same row
          const int i2 = d >> 1;
          const float cv = ct[s_ * 32 + i2], sv = st[s_ * 32 + i2];
          float outv = (d & 1) ? fmaf(p, sv, v * cv) : fmaf(-p, sv, v * cv);
          dst[((size_t)(b_ * 16 + h) * 2048 + s_) * 64 + d] = f2bf(outv * qsc);
        }
      }
    }
  } else {
    // v: write directly transposed [b][h][d][s]
#pragma unroll
    for (int mi = 0; mi < 4; mi++) {
#pragma unroll
      for (int ni = 0; ni < 4; ni++) {
        const int o = row_n + wn + ni * 16 + lq;
        const int oin = o & 1023, h = oin >> 6, d = oin & 63;
        const int t0 = row_m + wm + mi * 16 + g * 4;
        const int b_ = t0 >> 11, s_ = t0 & 2047;
        short4 pk;
        pk.x = f2bf(acc[mi][ni][0]); pk.y = f2bf(acc[mi][ni][1]);
        pk.z = f2bf(acc[mi][ni][2]); pk.w = f2bf(acc[mi][ni][3]);
        *(short4*)&vt[((size_t)(b_ * 16 + h) * 64 + d) * 2048 + s_] = pk;
      }
    }
  }
}

// ---------- K4: flash attention, 64 q/wave, merged straight-line A/B body, 3-slot ring ----------
// grid 512 x 256 thr (4 waves x 64 q), 2 blocks/CU. Per-tile body is ONE basic block in the
// common interior case (single full-skip guard + rare mask branch) so the scheduler can
// interleave SM(A) VALU with QK(B) MFMA and pack(B) with PV(A). Skip-merge is output-identical:
// the mask forces P=0 exactly for (q<L, kv>=L) tiles (exp2(-1e30*CSC) == 0, lacc += 0).
__global__ __launch_bounds__(256, 2) void k_attn(
    const short* __restrict__ qb, const short* __restrict__ kb, const short* __restrict__ vt,
    const int* __restrict__ seq_lens, short* __restrict__ ao)
{
  __shared__ short KV[24576];         // K slots [0,12288): s*4096 | V slots [12288,24576)
  const int n = blockIdx.x;           // 512 blocks
  const int m = n >> 3;
  const int bh = (n & 7) * 8 + (m & 7);   // 8 heads per XCD; K/V L2-resident
  const int qblk = m >> 3;                // 0..7
  const int b = bh >> 4, h = bh & 15;
  const int tid = threadIdx.x, lane = tid & 63, w = tid >> 6;   // w 0..3
  const int lq32 = lane & 31, hl = lane >> 5;
  const int L = seq_lens[b];
  const int q0 = qblk * 256 + w * 64;                     // wave's q base (64 rows)
  const int lr = lane >> 3, sc = (lane & 7) ^ (lr & 7);   // staging swizzle (src chunk)

  const short* kbase = kb + (size_t)bh * 2048 * 64;
  const short* vbase = vt + (size_t)bh * 64 * 2048;

  const short* qsrcA = qb + ((size_t)bh * 2048 + q0 + lq32) * 64 + 8 * hl;
  const short* qsrcB = qsrcA + 32 * 64;
  s8v qfA[4], qfB[4];
#pragma unroll
  for (int ki = 0; ki < 4; ki++) { qfA[ki] = *(const s8v*)&qsrcA[16 * ki];
                                   qfB[ki] = *(const s8v*)&qsrcB[16 * ki]; }

  f2v laccA[8], laccB[8];
#pragma unroll
  for (int i = 0; i < 8; i++) { laccA[i] = f2v{0.f, 0.f}; laccB[i] = f2v{0.f, 0.f}; }
  f16v OA[2], OB[2];
  OA[0] = f16v{0.f,0.f,0.f,0.f,0.f,0.f,0.f,0.f,0.f,0.f,0.f,0.f,0.f,0.f,0.f,0.f};
  OA[1] = OA[0]; OB[0] = OA[0]; OB[1] = OA[0];

  const bool blk_below = (qblk * 256 + 255) < L;
  const int nt = (blk_below ? ((L + 63) & ~63) : 2048) >> 6;   // tiles
  const bool belowB = (q0 + 63) < L;    // whole wave (both q-tiles) below L
  const int rsw = (lq32 & 7);

  auto stage = [&](int tile, int slot) {
    const int tn = tile * 64;
#pragma unroll
    for (int i = 0; i < 2; i++) {
      const int c = w * 2 + i;
      GLL16(kbase + (size_t)(tn + c * 8 + lr) * 64 + sc * 8, &KV[slot * 4096 + c * 512]);
      GLL16(vbase + (size_t)(c * 8 + lr) * 2048 + tn + sc * 8, &KV[12288 + slot * 4096 + c * 512]);
    }
  };

  // prologue: stage tiles 0 (and 1) into slots 0 (and 1)
  stage(0, 0);
  if (nt > 1) stage(1, 1);

  int sl = 0;                         // t % 3
  for (int t = 0; t < nt; t++) {
    if (t + 1 < nt) {
      asm volatile("s_waitcnt vmcnt(4)" ::: "memory");   // own tile-t loads drained
    } else {
      asm volatile("s_waitcnt vmcnt(0)" ::: "memory");
    }
    __builtin_amdgcn_sched_barrier(0);
    asm volatile("s_barrier" ::: "memory");              // t staged everywhere; t-1 fully read

    if (t + 2 < nt) {
      int sn = sl + 2; if (sn >= 3) sn -= 3;             // (t+2)%3 == (t-1)%3
      stage(t + 2, sn);
    }

    const int t0 = t * 64;
    if (!(belowB && t0 >= L)) {        // whole-wave skip only; partial cases handled by mask
      const short* Kc = &KV[sl * 4096];
      const short* Vc = &KV[12288 + sl * 4096];

      // ---- QK: hoist K frags once; 16 MFMAs over 4 independent chains ----
      s8v kf[2][4];
#pragma unroll
      for (int sub = 0; sub < 2; sub++)
#pragma unroll
        for (int ki = 0; ki < 4; ki++)
          kf[sub][ki] = *(const s8v*)&Kc[(sub * 32 + lq32) * 64 + (((2 * ki + hl) ^ rsw) * 8)];

      f16v saA[2], saB[2];
      const f16v zz = f16v{0.f,0.f,0.f,0.f,0.f,0.f,0.f,0.f,0.f,0.f,0.f,0.f,0.f,0.f,0.f,0.f};
      __builtin_amdgcn_s_setprio(1);
#pragma unroll
      for (int sub = 0; sub < 2; sub++) {
        f16v acc = zz;
#pragma unroll
        for (int ki = 0; ki < 4; ki++)
          acc = __builtin_amdgcn_mfma_f32_32x32x16_bf16(kf[sub][ki], qfA[ki], acc, 0, 0, 0);
        saA[sub] = acc;
      }
#pragma unroll
      for (int sub = 0; sub < 2; sub++) {
        f16v acc = zz;
#pragma unroll
        for (int ki = 0; ki < 4; ki++)
          acc = __builtin_amdgcn_mfma_f32_32x32x16_bf16(kf[sub][ki], qfB[ki], acc, 0, 0, 0);
        saB[sub] = acc;
      }
      __builtin_amdgcn_s_setprio(0);

      // ---- mask (rare wave-uniform branch: only tiles at/after the L boundary) ----
      if (t0 + 64 > L) {
        const bool qfreeA = ((q0 + lq32) >= L);
        const bool qfreeB = ((q0 + 32 + lq32) >= L);
#pragma unroll
        for (int sub = 0; sub < 2; sub++)
#pragma unroll
          for (int r = 0; r < 16; r++) {
            const int kvp = t0 + sub * 32 + (r & 3) + 8 * (r >> 2) + 4 * hl;
            const bool kin = kvp < L;
            if (!(qfreeA || kin)) saA[sub][r] = -1e30f;
            if (!(qfreeB || kin)) saB[sub][r] = -1e30f;
          }
      }

      // ---- SM A then B: exp2 + packed l accumulate (straight-line) ----
#pragma unroll
      for (int sub = 0; sub < 2; sub++)
#pragma unroll
        for (int r = 0; r < 16; r++)
          saA[sub][r] = __builtin_amdgcn_exp2f(saA[sub][r]);
#pragma unroll
      for (int r8 = 0; r8 < 8; r8++) {
        f2v a = f2v{saA[0][2 * r8], saA[0][2 * r8 + 1]};
        f2v c = f2v{saA[1][2 * r8], saA[1][2 * r8 + 1]};
        laccA[r8] += a + c;
      }
#pragma unroll
      for (int sub = 0; sub < 2; sub++)
#pragma unroll
        for (int r = 0; r < 16; r++)
          saB[sub][r] = __builtin_amdgcn_exp2f(saB[sub][r]);
#pragma unroll
      for (int r8 = 0; r8 < 8; r8++) {
        f2v a = f2v{saB[0][2 * r8], saB[0][2 * r8 + 1]};
        f2v c = f2v{saB[1][2 * r8], saB[1][2 * r8 + 1]};
        laccB[r8] += a + c;
      }

      // ---- PV: hoist V frags once; pack A (T12) + 8 MFMA, pack B + 8 MFMA ----
      s8v vf[2][2][2];
#pragma unroll
      for (int sub = 0; sub < 2; sub++)
#pragma unroll
        for (int dt = 0; dt < 2; dt++) {
          vf[sub][0][dt] = *(const s8v*)&Vc[(32 * dt + lq32) * 64 + (((4 * sub + hl) ^ rsw) * 8)];
          vf[sub][1][dt] = *(const s8v*)&Vc[(32 * dt + lq32) * 64 + (((4 * sub + 2 + hl) ^ rsw) * 8)];
        }
      union P8 { unsigned u[4]; s8v s; };
      __builtin_amdgcn_s_setprio(1);
#pragma unroll
      for (int sub = 0; sub < 2; sub++) {
        unsigned c0 = cvtpk(saA[sub][0],  saA[sub][1]);
        unsigned c1 = cvtpk(saA[sub][2],  saA[sub][3]);
        unsigned c2 = cvtpk(saA[sub][4],  saA[sub][5]);
        unsigned c3 = cvtpk(saA[sub][6],  saA[sub][7]);
        plswap(c0, c2);
        plswap(c1, c3);
        unsigned c4 = cvtpk(saA[sub][8],  saA[sub][9]);
        unsigned c5 = cvtpk(saA[sub][10], saA[sub][11]);
        unsigned c6 = cvtpk(saA[sub][12], saA[sub][13]);
        unsigned c7 = cvtpk(saA[sub][14], saA[sub][15]);
        plswap(c4, c6);
        plswap(c5, c7);
        P8 pa, pb;
        pa.u[0] = c0; pa.u[1] = c1; pa.u[2] = c2; pa.u[3] = c3;   // kv sub*32 + 8hl + e
        pb.u[0] = c4; pb.u[1] = c5; pb.u[2] = c6; pb.u[3] = c7;   // kv sub*32 + 16 + 8hl + e
#pragma unroll
        for (int dt = 0; dt < 2; dt++) {
          OA[dt] = __builtin_amdgcn_mfma_f32_32x32x16_bf16(vf[sub][0][dt], pa.s, OA[dt], 0, 0, 0);
          OA[dt] = __builtin_amdgcn_mfma_f32_32x32x16_bf16(vf[sub][1][dt], pb.s, OA[dt], 0, 0, 0);
        }
      }
#pragma unroll
      for (int sub = 0; sub < 2; sub++) {
        unsigned c0 = cvtpk(saB[sub][0],  saB[sub][1]);
        unsigned c1 = cvtpk(saB[sub][2],  saB[sub][3]);
        unsigned c2 = cvtpk(saB[sub][4],  saB[sub][5]);
        unsigned c3 = cvtpk(saB[sub][6],  saB[sub][7]);
        plswap(c0, c2);
        plswap(c1, c3);
        unsigned c4 = cvtpk(saB[sub][8],  saB[sub][9]);
        unsigned c5 = cvtpk(saB[sub][10], saB[sub][11]);
        unsigned c6 = cvtpk(saB[sub][12], saB[sub][13]);
        unsigned c7 = cvtpk(saB[sub][14], saB[sub][15]);
        plswap(c4, c6);
        plswap(c5, c7);
        P8 pa, pb;
        pa.u[0] = c0; pa.u[1] = c1; pa.u[2] = c2; pa.u[3] = c3;
        pb.u[0] = c4; pb.u[1] = c5; pb.u[2] = c6; pb.u[3] = c7;
#pragma unroll
        for (int dt = 0; dt < 2; dt++) {
          OB[dt] = __builtin_amdgcn_mfma_f32_32x32x16_bf16(vf[sub][0][dt], pa.s, OB[dt], 0, 0, 0);
          OB[dt] = __builtin_amdgcn_mfma_f32_32x32x16_bf16(vf[sub][1][dt], pb.s, OB[dt], 0, 0, 0);
        }
      }
      __builtin_amdgcn_s_setprio(0);
    }

    if (++sl == 3) sl = 0;
  }

  // ---- epilogue: per q-tile l merge + normalize + O^T->[q][d] via reused K-slot LDS ----
  f2v l2 = (laccA[0] + laccA[1]) + (laccA[2] + laccA[3]);
  f2v l3 = (laccA[4] + laccA[5]) + (laccA[6] + laccA[7]);
  l2 += l3;
  float lA = l2.x + l2.y;
  lA += __shfl_xor(lA, 32);
  const float invA = 1.0f / lA;
  l2 = (laccB[0] + laccB[1]) + (laccB[2] + laccB[3]);
  l3 = (laccB[4] + laccB[5]) + (laccB[6] + laccB[7]);
  l2 += l3;
  float lB = l2.x + l2.y;
  lB += __shfl_xor(lB, 32);
  const float invB = 1.0f / lB;

  asm volatile("s_barrier" ::: "memory");   // all waves done with K slots before reuse
  short* es = &KV[w * 2048];   // 32 rows x 64 shorts, chunk-XOR swizzled (per-wave)

  // pass A (rows q0..q0+31)
#pragma unroll
  for (int dt = 0; dt < 2; dt++)
#pragma unroll
    for (int rp = 0; rp < 8; rp++) {
      unsigned u = cvtpk(OA[dt][2 * rp] * invA, OA[dt][2 * rp + 1] * invA);
      const int col = 32 * dt + 8 * (rp >> 1) + 2 * (rp & 1) + 4 * hl;
      const int chunk = col >> 3, within = col & 7;
      *(unsigned*)&es[lq32 * 64 + ((chunk ^ (lq32 & 7)) << 3) + within] = u;
    }
  asm volatile("" ::: "memory");
#pragma unroll
  for (int pph = 0; pph < 4; pph++) {
    const int qq = pph * 8 + lr;
    const int ch = lane & 7;
    s8v vv = *(const s8v*)&es[qq * 64 + ((ch ^ lr) << 3)];
    *(s8v*)&ao[((size_t)b * 2048 + q0 + qq) * 1024 + h * 64 + ch * 8] = vv;
  }
  asm volatile("" ::: "memory");   // pass-A reads complete before pass-B writes (in-wave)

  // pass B (rows q0+32..q0+63)
#pragma unroll
  for (int dt = 0; dt < 2; dt++)
#pragma unroll
    for (int rp = 0; rp < 8; rp++) {
      unsigned u = cvtpk(OB[dt][2 * rp] * invB, OB[dt][2 * rp + 1] * invB);
      const int col = 32 * dt + 8 * (rp >> 1) + 2 * (rp & 1) + 4 * hl;
      const int chunk = col >> 3, within = col & 7;
      *(unsigned*)&es[lq32 * 64 + ((chunk ^ (lq32 & 7)) << 3) + within] = u;
    }
  asm volatile("" ::: "memory");
#pragma unroll
  for (int pph = 0; pph < 4; pph++) {
    const int qq = pph * 8 + lr;
    const int ch = lane & 7;
    s8v vv = *(const s8v*)&es[qq * 64 + ((ch ^ lr) << 3)];
    *(s8v*)&ao[((size_t)b * 2048 + q0 + 32 + qq) * 1024 + h * 64 + ch * 8] = vv;
  }
}

// ---------- K5: output GEMM 128x128 tile, 4 waves, dbuf + counted vmcnt -> fp32 ----------
__global__ __launch_bounds__(256, 2) void k_gemm_out(
    const short* __restrict__ ab, const short* __restrict__ wob, float* __restrict__ out)
{
  __shared__ short As[2][128 * 64];
  __shared__ short Bs[2][128 * 64];
  const int bid = blockIdx.x;
  const int item = (bid & 7) * 64 + (bid >> 3);    // XCD-bijective (512 = 8*64)
  const int row_m = (item & 63) * 128;
  const int row_n = (item >> 6) * 128;
  const int tid = threadIdx.x;
  const int lane = tid & 63, w = tid >> 6;
  const int g = lane >> 4, lq = lane & 15;
  const int wm = (w >> 1) * 64, wn = (w & 1) * 64;
  const int srow = tid >> 3;
  const int schunk = (lane & 7) ^ ((lane >> 3) & 7);

  f4v acc[4][4];
#pragma unroll
  for (int i = 0; i < 4; i++)
#pragma unroll
    for (int jj = 0; jj < 4; jj++) acc[i][jj] = f4v{0.f, 0.f, 0.f, 0.f};

  auto stage = [&](int kt, int s) {
#pragma unroll
    for (int jj = 0; jj < 4; jj++)
      GLL16(ab + (size_t)(row_m + jj * 32 + srow) * 1024 + kt + schunk * 8,
            &As[s][jj * 2048 + w * 512]);
#pragma unroll
    for (int jj = 0; jj < 4; jj++)
      GLL16(wob + (size_t)(row_n + jj * 32 + srow) * 1024 + kt + schunk * 8,
            &Bs[s][jj * 2048 + w * 512]);
  };

  stage(0, 0);
  stage(64, 1);
  asm volatile("s_waitcnt vmcnt(8)" ::: "memory");
  __builtin_amdgcn_sched_barrier(0);
  asm volatile("s_barrier" ::: "memory");

  for (int t = 0; t < 16; t++) {
    const int s = t & 1;
    const short* Ac = &As[s][0];
    const short* Bc = &Bs[s][0];
#pragma unroll
    for (int kk = 0; kk < 2; kk++) {
      s8v a[4], b[4];
#pragma unroll
      for (int mi = 0; mi < 4; mi++) {
        const int r_ = wm + mi * 16 + lq;
        a[mi] = *(const s8v*)&Ac[r_ * 64 + (((kk * 4 + g) ^ (lq & 7)) * 8)];
      }
#pragma unroll
      for (int ni = 0; ni < 4; ni++) {
        const int r_ = wn + ni * 16 + lq;
        b[ni] = *(const s8v*)&Bc[r_ * 64 + (((kk * 4 + g) ^ (lq & 7)) * 8)];
      }
      __builtin_amdgcn_s_setprio(1);
#pragma unroll
      for (int mi = 0; mi < 4; mi++)
#pragma unroll
        for (int ni = 0; ni < 4; ni++)
          acc[mi][ni] = __builtin_amdgcn_mfma_f32_16x16x32_bf16(a[mi], b[ni], acc[mi][ni], 0, 0, 0);
      __builtin_amdgcn_s_setprio(0);
    }
    if (t < 15) {
      asm volatile("s_waitcnt lgkmcnt(0)" ::: "memory");
      asm volatile("s_barrier" ::: "memory");
      if (t < 14) {
        stage((t + 2) * 64, s);
        asm volatile("s_waitcnt vmcnt(8)" ::: "memory");
      } else {
        asm volatile("s_waitcnt vmcnt(0)" ::: "memory");
      }
      __builtin_amdgcn_sched_barrier(0);
      asm volatile("s_barrier" ::: "memory");
    }
  }

#pragma unroll
  for (int mi = 0; mi < 4; mi++)
#pragma unroll
    for (int ni = 0; ni < 4; ni++) {
      const int o = row_n + wn + ni * 16 + lq;
#pragma unroll
      for (int r = 0; r < 4; r++) {
        const int tt = row_m + wm + mi * 16 + g * 4 + r;
        out[(size_t)tt * 1024 + o] = acc[mi][ni][r];
      }
    }
}

extern "C" void kernel_launch(void* const* d_in, const int* in_sizes, int n_in,
                              void* d_out, int out_size, void* d_ws, size_t ws_size,
                              hipStream_t stream) {
  const float* x  = (const float*)d_in[0];
  const int*   sl = (const int*)d_in[1];
  const float* wq = (const float*)d_in[2];
  const float* wk = (const float*)d_in[3];
  const float* wv = (const float*)d_in[4];
  const float* wo = (const float*)d_in[5];
  float* out = (float*)d_out;

  char* ws = (char*)d_ws;
  float* ct   = (float*)(ws + 0);          //   262144 B
  float* st   = (float*)(ws + 262144);     //   262144 B
  short* xb   = (short*)(ws + 524288);     // 16777216 B  [8192][1024]
  short* wqkv = (short*)(ws + 17301504);   //  6291456 B  [3072][1024]
  short* wob  = (short*)(ws + 23592960);   //  2097152 B  [1024][1024]
  short* qb   = (short*)(ws + 25690112);   // 16777216 B  [4][16][2048][64]
  short* kbf  = (short*)(ws + 42467328);   // 16777216 B
  short* vtb  = (short*)(ws + 76021760);   // 16777216 B  [4][16][64][2048]
  short* ab   = (short*)(ws + 92798976);   // 16777216 B  [8192][1024]
  // total 109,576,192 B

  k_prep<<<12544, 256, 0, stream>>>(x, wq, wk, wv, wo, ct, st, xb, wqkv, wob);
  k_gemm_qkv<<<1536, 256, 0, stream>>>(xb, wqkv, ct, st, qb, kbf, vtb);
  k_attn<<<512, 256, 0, stream>>>(qb, kbf, vtb, sl, ab);
  k_gemm_out<<<512, 256, 0, stream>>>(ab, wob, out);
}

// Round 18
// 173.188 us; speedup vs baseline: 1.0622x; 1.0622x over previous
//
#include <hip/hip_runtime.h>
#include <hip/hip_bf16.h>
#include <stdint.h>

// Attention_37031208026285: x[4,2048,1024] fp32, seq_lens[4] i32, wq/wk/wv/wo[1024,1024] fp32
// out = softmax_masked((rope(x@wq.T)) @ rope(x@wk.T)^T / 8) @ (x@wv.T) @ wo.T   (fp32 out)
// ROUND 18 = exact revert to the round-16 configuration (best measured: 174.4 us).

typedef __attribute__((ext_vector_type(8))) short s8v;
typedef __attribute__((ext_vector_type(2))) float f2v;
typedef __attribute__((ext_vector_type(4))) float f4v;
typedef __attribute__((ext_vector_type(16))) float f16v;

#define GLL16(gsrc, ldst) __builtin_amdgcn_global_load_lds(              \
    (const __attribute__((address_space(1))) void*)(gsrc),               \
    (__attribute__((address_space(3))) void*)(ldst), 16, 0, 0)

__device__ __forceinline__ short f2bf(float f) {
  union { float f; unsigned i; } v; v.f = f;
  unsigned r = v.i + 0x7fffu + ((v.i >> 16) & 1u);
  return (short)(r >> 16);
}
__device__ __forceinline__ unsigned cvtpk(float a, float b) {
  unsigned r;
  asm("v_cvt_pk_bf16_f32 %0, %1, %2" : "=v"(r) : "v"(a), "v"(b));
  return r;
}
__device__ __forceinline__ void plswap(unsigned& x, unsigned& y) {
  asm volatile("v_permlane32_swap_b32 %0, %1" : "+v"(x), "+v"(y));
}

// ---------- K0: merged prep: rope tables + all fp32->bf16 conversions (1 launch) ----------
__global__ __launch_bounds__(256) void k_prep(
    const float* __restrict__ x,
    const float* __restrict__ wq, const float* __restrict__ wk,
    const float* __restrict__ wv, const float* __restrict__ wo,
    float* __restrict__ ct, float* __restrict__ st,
    short* __restrict__ xb, short* __restrict__ wqkv, short* __restrict__ wob)
{
  int id = blockIdx.x * 256 + threadIdx.x;
  if (id < 65536) {
    const int pos = id >> 5, i = id & 31;
    float inv = exp2f(-13.287712379549449f * ((float)i / 32.0f)); // 10000^(-i/32)
    float a = (float)pos * inv;
    float s, c;
    sincosf(a, &s, &c);
    ct[id] = c; st[id] = s;
    return;
  }
  id -= 65536;
  if (id < 2097152) {
    float4 v = ((const float4*)x)[id];
    short4 o;
    o.x = f2bf(v.x); o.y = f2bf(v.y); o.z = f2bf(v.z); o.w = f2bf(v.w);
    ((short4*)xb)[id] = o;
    return;
  }
  id -= 2097152;
  const int sel = id >> 18;            // 0=wq 1=wk 2=wv 3=wo
  const int off = id & 262143;
  const float* src = (sel == 0) ? wq : (sel == 1) ? wk : (sel == 2) ? wv : wo;
  short* dst = (sel < 3) ? (wqkv + (size_t)sel * 1048576) : wob;
  float4 v = ((const float4*)src)[off];
  short4 o;
  o.x = f2bf(v.x); o.y = f2bf(v.y); o.z = f2bf(v.z); o.w = f2bf(v.w);
  ((short4*)dst)[off] = o;
}

// ---------- K2: QKV GEMM 128x128 tile, 4 waves, dbuf + counted vmcnt, T2 swizzle ----------
// Intra-XCD L2 supertiling (8 supertiles of 8m x 3n, 2.75 MB footprint).
// Direct-store epilogue: RoPE for q/k (q pre-scaled by 0.125*log2e), v written transposed.
__global__ __launch_bounds__(256, 2) void k_gemm_qkv(
    const short* __restrict__ xb, const short* __restrict__ wb,
    const float* __restrict__ ct, const float* __restrict__ st,
    short* __restrict__ qb, short* __restrict__ kb, short* __restrict__ vt)
{
  __shared__ short As[2][128 * 64];
  __shared__ short Bs[2][128 * 64];
  const int bid = blockIdx.x;
  const int j = bid >> 3;                     // 0..191 within XCD
  const int stile = j / 24;                   // 8 supertiles
  const int r0 = j - stile * 24;              // 0..23 = 8 m x 3 n
  const int row_m = (stile * 8 + (r0 & 7)) * 128;
  const int row_n = ((bid & 7) * 3 + (r0 >> 3)) * 128;
  const int tid = threadIdx.x;
  const int lane = tid & 63, w = tid >> 6;
  const int g = lane >> 4, lq = lane & 15;
  const int wm = (w >> 1) * 64, wn = (w & 1) * 64;
  const int srow = tid >> 3;                       // 0..31
  const int schunk = (lane & 7) ^ ((lane >> 3) & 7);

  f4v acc[4][4];
#pragma unroll
  for (int i = 0; i < 4; i++)
#pragma unroll
    for (int jj = 0; jj < 4; jj++) acc[i][jj] = f4v{0.f, 0.f, 0.f, 0.f};

  auto stage = [&](int kt, int s) {
#pragma unroll
    for (int jj = 0; jj < 4; jj++)
      GLL16(xb + (size_t)(row_m + jj * 32 + srow) * 1024 + kt + schunk * 8,
            &As[s][jj * 2048 + w * 512]);
#pragma unroll
    for (int jj = 0; jj < 4; jj++)
      GLL16(wb + (size_t)(row_n + jj * 32 + srow) * 1024 + kt + schunk * 8,
            &Bs[s][jj * 2048 + w * 512]);
  };

  stage(0, 0);
  stage(64, 1);
  asm volatile("s_waitcnt vmcnt(8)" ::: "memory");
  __builtin_amdgcn_sched_barrier(0);
  asm volatile("s_barrier" ::: "memory");

  for (int t = 0; t < 16; t++) {
    const int s = t & 1;
    const short* Ac = &As[s][0];
    const short* Bc = &Bs[s][0];
#pragma unroll
    for (int kk = 0; kk < 2; kk++) {
      s8v a[4], b[4];
#pragma unroll
      for (int mi = 0; mi < 4; mi++) {
        const int r_ = wm + mi * 16 + lq;
        a[mi] = *(const s8v*)&Ac[r_ * 64 + (((kk * 4 + g) ^ (lq & 7)) * 8)];
      }
#pragma unroll
      for (int ni = 0; ni < 4; ni++) {
        const int r_ = wn + ni * 16 + lq;
        b[ni] = *(const s8v*)&Bc[r_ * 64 + (((kk * 4 + g) ^ (lq & 7)) * 8)];
      }
      __builtin_amdgcn_s_setprio(1);
#pragma unroll
      for (int mi = 0; mi < 4; mi++)
#pragma unroll
        for (int ni = 0; ni < 4; ni++)
          acc[mi][ni] = __builtin_amdgcn_mfma_f32_16x16x32_bf16(a[mi], b[ni], acc[mi][ni], 0, 0, 0);
      __builtin_amdgcn_s_setprio(0);
    }
    if (t < 15) {
      asm volatile("s_waitcnt lgkmcnt(0)" ::: "memory");
      asm volatile("s_barrier" ::: "memory");             // all waves done reading slot s
      if (t < 14) {
        stage((t + 2) * 64, s);
        asm volatile("s_waitcnt vmcnt(8)" ::: "memory");  // t+1 landed; t+2 in flight
      } else {
        asm volatile("s_waitcnt vmcnt(0)" ::: "memory");
      }
      __builtin_amdgcn_sched_barrier(0);
      asm volatile("s_barrier" ::: "memory");             // slot s^1 ready
    }
  }

  // Epilogue. C element (t,o): t = row_m+wm+mi*16+g*4+r, o = row_n+wn+ni*16+lq
  const int sel = row_n >> 10;   // 0=q 1=k 2=v (128-tiles don't straddle)
  if (sel < 2) {
    const float qsc = (sel == 0) ? 0.18033688011112042f : 1.0f;  // fold 1/8*log2e into q
    short* __restrict__ dst = (sel == 0) ? qb : kb;
#pragma unroll
    for (int mi = 0; mi < 4; mi++) {
#pragma unroll
      for (int ni = 0; ni < 4; ni++) {
        const int o = row_n + wn + ni * 16 + lq;
        const int oin = o & 1023, h = oin >> 6, d = oin & 63;
#pragma unroll
        for (int r = 0; r < 4; r++) {
          const int tt = row_m + wm + mi * 16 + g * 4 + r;
          const int b_ = tt >> 11, s_ = tt & 2047;
          float v = acc[mi][ni][r];
          float p = __shfl_xor(v, 1);          // pair partner (o^1), same row
          const int i2 = d >> 1;
          const float cv = ct[s_ * 32 + i2], sv = st[s_ * 32 + i2];
          float outv = (d & 1) ? fmaf(p, sv, v * cv) : fmaf(-p, sv, v * cv);
          dst[((size_t)(b_ * 16 + h) * 2048 + s_) * 64 + d] = f2bf(outv * qsc);
        }
      }
    }
  } else {
    // v: write directly transposed [b][h][d][s]
#pragma unroll
    for (int mi = 0; mi < 4; mi++) {
#pragma unroll
      for (int ni = 0; ni < 4; ni++) {
        const int o = row_n + wn + ni * 16 + lq;
        const int oin = o & 1023, h = oin >> 6, d = oin & 63;
        const int t0 = row_m + wm + mi * 16 + g * 4;
        const int b_ = t0 >> 11, s_ = t0 & 2047;
        short4 pk;
        pk.x = f2bf(acc[mi][ni][0]); pk.y = f2bf(acc[mi][ni][1]);
        pk.z = f2bf(acc[mi][ni][2]); pk.w = f2bf(acc[mi][ni][3]);
        *(short4*)&vt[((size_t)(b_ * 16 + h) * 64 + d) * 2048 + s_] = pk;
      }
    }
  }
}

// ---------- K4: flash attention, 64 q/wave, phase-fused A/B pipeline, 3-slot KV ring ----------
__global__ __launch_bounds__(256, 2) void k_attn(
    const short* __restrict__ qb, const short* __restrict__ kb, const short* __restrict__ vt,
    const int* __restrict__ seq_lens, short* __restrict__ ao)
{
  __shared__ short KV[24576];         // K slots [0,12288): s*4096 | V slots [12288,24576)
  const int n = blockIdx.x;           // 512 blocks
  const int m = n >> 3;
  const int bh = (n & 7) * 8 + (m & 7);   // 8 heads per XCD; K/V L2-resident
  const int qblk = m >> 3;                // 0..7
  const int b = bh >> 4, h = bh & 15;
  const int tid = threadIdx.x, lane = tid & 63, w = tid >> 6;   // w 0..3
  const int lq32 = lane & 31, hl = lane >> 5;
  const int L = seq_lens[b];
  const int q0 = qblk * 256 + w * 64;                     // wave's q base (64 rows)
  const int lr = lane >> 3, sc = (lane & 7) ^ (lr & 7);   // staging swizzle (src chunk)

  const short* kbase = kb + (size_t)bh * 2048 * 64;
  const short* vbase = vt + (size_t)bh * 64 * 2048;

  const short* qsrcA = qb + ((size_t)bh * 2048 + q0 + lq32) * 64 + 8 * hl;
  const short* qsrcB = qsrcA + 32 * 64;
  s8v qfA[4], qfB[4];
#pragma unroll
  for (int ki = 0; ki < 4; ki++) { qfA[ki] = *(const s8v*)&qsrcA[16 * ki];
                                   qfB[ki] = *(const s8v*)&qsrcB[16 * ki]; }

  f2v laccA[8], laccB[8];
#pragma unroll
  for (int i = 0; i < 8; i++) { laccA[i] = f2v{0.f, 0.f}; laccB[i] = f2v{0.f, 0.f}; }
  f16v OA[2], OB[2];
  OA[0] = f16v{0.f,0.f,0.f,0.f,0.f,0.f,0.f,0.f,0.f,0.f,0.f,0.f,0.f,0.f,0.f,0.f};
  OA[1] = OA[0]; OB[0] = OA[0]; OB[1] = OA[0];

  const bool blk_below = (qblk * 256 + 255) < L;
  const int nt = (blk_below ? ((L + 63) & ~63) : 2048) >> 6;   // tiles
  const bool belowA = (q0 + 31) < L;    // q-tile A fully below L
  const bool belowB = (q0 + 63) < L;    // q-tile B fully below L
  const int rsw = (lq32 & 7);

  auto stage = [&](int tile, int slot) {
    const int tn = tile * 64;
#pragma unroll
    for (int i = 0; i < 2; i++) {
      const int c = w * 2 + i;
      GLL16(kbase + (size_t)(tn + c * 8 + lr) * 64 + sc * 8, &KV[slot * 4096 + c * 512]);
      GLL16(vbase + (size_t)(c * 8 + lr) * 2048 + tn + sc * 8, &KV[12288 + slot * 4096 + c * 512]);
    }
  };

  // mask + exp2 + l-accumulate for one q-tile
  auto smx = [&](f16v (&sa)[2], f2v (&lacc)[8], int q0l, int t0) {
    const bool nomask = (t0 + 64 <= L) || (q0l >= L);
    if (!nomask) {
      const bool qfree = ((q0l + lq32) >= L);
#pragma unroll
      for (int sub = 0; sub < 2; sub++)
#pragma unroll
        for (int r = 0; r < 16; r++) {
          const int kvp = t0 + sub * 32 + (r & 3) + 8 * (r >> 2) + 4 * hl;
          if (!(qfree || kvp < L)) sa[sub][r] = -1e30f;
        }
    }
#pragma unroll
    for (int sub = 0; sub < 2; sub++)
#pragma unroll
      for (int r = 0; r < 16; r++)
        sa[sub][r] = __builtin_amdgcn_exp2f(sa[sub][r]);
#pragma unroll
    for (int r8 = 0; r8 < 8; r8++) {
      f2v a = f2v{sa[0][2 * r8], sa[0][2 * r8 + 1]};
      f2v c = f2v{sa[1][2 * r8], sa[1][2 * r8 + 1]};
      lacc[r8] += a + c;
    }
  };

  // pack P (T12) + PV MFMAs for one q-tile, using hoisted V fragments vf[sub][j][dt]
  auto pv = [&](f16v (&sa)[2], f16v (&O)[2], const s8v (&vf)[2][2][2]) {
#pragma unroll
    for (int sub = 0; sub < 2; sub++) {
      unsigned c0 = cvtpk(sa[sub][0],  sa[sub][1]);
      unsigned c1 = cvtpk(sa[sub][2],  sa[sub][3]);
      unsigned c2 = cvtpk(sa[sub][4],  sa[sub][5]);
      unsigned c3 = cvtpk(sa[sub][6],  sa[sub][7]);
      plswap(c0, c2);
      plswap(c1, c3);
      unsigned c4 = cvtpk(sa[sub][8],  sa[sub][9]);
      unsigned c5 = cvtpk(sa[sub][10], sa[sub][11]);
      unsigned c6 = cvtpk(sa[sub][12], sa[sub][13]);
      unsigned c7 = cvtpk(sa[sub][14], sa[sub][15]);
      plswap(c4, c6);
      plswap(c5, c7);
      union P8 { unsigned u[4]; s8v s; };
      P8 pa, pb;
      pa.u[0] = c0; pa.u[1] = c1; pa.u[2] = c2; pa.u[3] = c3;   // kv sub*32 + 8hl + e
      pb.u[0] = c4; pb.u[1] = c5; pb.u[2] = c6; pb.u[3] = c7;   // kv sub*32 + 16 + 8hl + e
#pragma unroll
      for (int dt = 0; dt < 2; dt++) {
        O[dt] = __builtin_amdgcn_mfma_f32_32x32x16_bf16(vf[sub][0][dt], pa.s, O[dt], 0, 0, 0);
        O[dt] = __builtin_amdgcn_mfma_f32_32x32x16_bf16(vf[sub][1][dt], pb.s, O[dt], 0, 0, 0);
      }
    }
  };

  // prologue: stage tiles 0 (and 1) into slots 0 (and 1)
  stage(0, 0);
  if (nt > 1) stage(1, 1);

  int sl = 0;                         // t % 3
  for (int t = 0; t < nt; t++) {
    if (t + 1 < nt) {
      asm volatile("s_waitcnt vmcnt(4)" ::: "memory");   // own tile-t loads drained
    } else {
      asm volatile("s_waitcnt vmcnt(0)" ::: "memory");
    }
    __builtin_amdgcn_sched_barrier(0);
    asm volatile("s_barrier" ::: "memory");              // t staged everywhere; t-1 fully read

    if (t + 2 < nt) {
      int sn = sl + 2; if (sn >= 3) sn -= 3;             // (t+2)%3 == (t-1)%3
      stage(t + 2, sn);
    }

    const int t0 = t * 64;
    const short* Kc = &KV[sl * 4096];
    const short* Vc = &KV[12288 + sl * 4096];
    const bool doA = !(belowA && t0 >= L);
    const bool doB = !(belowB && t0 >= L);

    if (doA || doB) {
      // ---- QK phase: hoist K frags once, 16 MFMAs over 4 independent chains ----
      s8v kf[2][4];
#pragma unroll
      for (int sub = 0; sub < 2; sub++)
#pragma unroll
        for (int ki = 0; ki < 4; ki++)
          kf[sub][ki] = *(const s8v*)&Kc[(sub * 32 + lq32) * 64 + (((2 * ki + hl) ^ rsw) * 8)];

      f16v saA[2], saB[2];
      const f16v zz = f16v{0.f,0.f,0.f,0.f,0.f,0.f,0.f,0.f,0.f,0.f,0.f,0.f,0.f,0.f,0.f,0.f};
      __builtin_amdgcn_s_setprio(1);
      if (doA) {
#pragma unroll
        for (int sub = 0; sub < 2; sub++) {
          f16v acc = zz;
#pragma unroll
          for (int ki = 0; ki < 4; ki++)
            acc = __builtin_amdgcn_mfma_f32_32x32x16_bf16(kf[sub][ki], qfA[ki], acc, 0, 0, 0);
          saA[sub] = acc;
        }
      }
      if (doB) {
#pragma unroll
        for (int sub = 0; sub < 2; sub++) {
          f16v acc = zz;
#pragma unroll
          for (int ki = 0; ki < 4; ki++)
            acc = __builtin_amdgcn_mfma_f32_32x32x16_bf16(kf[sub][ki], qfB[ki], acc, 0, 0, 0);
          saB[sub] = acc;
        }
      }
      __builtin_amdgcn_s_setprio(0);

      // ---- SM phase (VALU block; staggered waves cover the MFMA pipe) ----
      if (doA) smx(saA, laccA, q0, t0);
      if (doB) smx(saB, laccB, q0 + 32, t0);

      // ---- PV phase: hoist V frags once; pack+MFMA A, pack+MFMA B ----
      s8v vf[2][2][2];
#pragma unroll
      for (int sub = 0; sub < 2; sub++)
#pragma unroll
        for (int dt = 0; dt < 2; dt++) {
          vf[sub][0][dt] = *(const s8v*)&Vc[(32 * dt + lq32) * 64 + (((4 * sub + hl) ^ rsw) * 8)];
          vf[sub][1][dt] = *(const s8v*)&Vc[(32 * dt + lq32) * 64 + (((4 * sub + 2 + hl) ^ rsw) * 8)];
        }
      __builtin_amdgcn_s_setprio(1);
      if (doA) pv(saA, OA, vf);
      if (doB) pv(saB, OB, vf);
      __builtin_amdgcn_s_setprio(0);
    }

    if (++sl == 3) sl = 0;
  }

  // ---- epilogue: per q-tile l merge + normalize + O^T->[q][d] via reused K-slot LDS ----
  f2v l2 = (laccA[0] + laccA[1]) + (laccA[2] + laccA[3]);
  f2v l3 = (laccA[4] + laccA[5]) + (laccA[6] + laccA[7]);
  l2 += l3;
  float lA = l2.x + l2.y;
  lA += __shfl_xor(lA, 32);
  const float invA = 1.0f / lA;
  l2 = (laccB[0] + laccB[1]) + (laccB[2] + laccB[3]);
  l3 = (laccB[4] + laccB[5]) + (laccB[6] + laccB[7]);
  l2 += l3;
  float lB = l2.x + l2.y;
  lB += __shfl_xor(lB, 32);
  const float invB = 1.0f / lB;

  asm volatile("s_barrier" ::: "memory");   // all waves done with K slots before reuse
  short* es = &KV[w * 2048];   // 32 rows x 64 shorts, chunk-XOR swizzled (per-wave)

  // pass A (rows q0..q0+31)
#pragma unroll
  for (int dt = 0; dt < 2; dt++)
#pragma unroll
    for (int rp = 0; rp < 8; rp++) {
      unsigned u = cvtpk(OA[dt][2 * rp] * invA, OA[dt][2 * rp + 1] * invA);
      const int col = 32 * dt + 8 * (rp >> 1) + 2 * (rp & 1) + 4 * hl;
      const int chunk = col >> 3, within = col & 7;
      *(unsigned*)&es[lq32 * 64 + ((chunk ^ (lq32 & 7)) << 3) + within] = u;
    }
  asm volatile("" ::: "memory");
#pragma unroll
  for (int pph = 0; pph < 4; pph++) {
    const int qq = pph * 8 + lr;
    const int ch = lane & 7;
    s8v vv = *(const s8v*)&es[qq * 64 + ((ch ^ lr) << 3)];
    *(s8v*)&ao[((size_t)b * 2048 + q0 + qq) * 1024 + h * 64 + ch * 8] = vv;
  }
  asm volatile("" ::: "memory");   // pass-A reads complete before pass-B writes (in-wave)

  // pass B (rows q0+32..q0+63)
#pragma unroll
  for (int dt = 0; dt < 2; dt++)
#pragma unroll
    for (int rp = 0; rp < 8; rp++) {
      unsigned u = cvtpk(OB[dt][2 * rp] * invB, OB[dt][2 * rp + 1] * invB);
      const int col = 32 * dt + 8 * (rp >> 1) + 2 * (rp & 1) + 4 * hl;
      const int chunk = col >> 3, within = col & 7;
      *(unsigned*)&es[lq32 * 64 + ((chunk ^ (lq32 & 7)) << 3) + within] = u;
    }
  asm volatile("" ::: "memory");
#pragma unroll
  for (int pph = 0; pph < 4; pph++) {
    const int qq = pph * 8 + lr;
    const int ch = lane & 7;
    s8v vv = *(const s8v*)&es[qq * 64 + ((ch ^ lr) << 3)];
    *(s8v*)&ao[((size_t)b * 2048 + q0 + 32 + qq) * 1024 + h * 64 + ch * 8] = vv;
  }
}

// ---------- K5: output GEMM 128x128 tile, 4 waves, dbuf + counted vmcnt -> fp32 ----------
__global__ __launch_bounds__(256, 2) void k_gemm_out(
    const short* __restrict__ ab, const short* __restrict__ wob, float* __restrict__ out)
{
  __shared__ short As[2][128 * 64];
  __shared__ short Bs[2][128 * 64];
  const int bid = blockIdx.x;
  const int item = (bid & 7) * 64 + (bid >> 3);    // XCD-bijective (512 = 8*64)
  const int row_m = (item & 63) * 128;
  const int row_n = (item >> 6) * 128;
  const int tid = threadIdx.x;
  const int lane = tid & 63, w = tid >> 6;
  const int g = lane >> 4, lq = lane & 15;
  const int wm = (w >> 1) * 64, wn = (w & 1) * 64;
  const int srow = tid >> 3;
  const int schunk = (lane & 7) ^ ((lane >> 3) & 7);

  f4v acc[4][4];
#pragma unroll
  for (int i = 0; i < 4; i++)
#pragma unroll
    for (int jj = 0; jj < 4; jj++) acc[i][jj] = f4v{0.f, 0.f, 0.f, 0.f};

  auto stage = [&](int kt, int s) {
#pragma unroll
    for (int jj = 0; jj < 4; jj++)
      GLL16(ab + (size_t)(row_m + jj * 32 + srow) * 1024 + kt + schunk * 8,
            &As[s][jj * 2048 + w * 512]);
#pragma unroll
    for (int jj = 0; jj < 4; jj++)
      GLL16(wob + (size_t)(row_n + jj * 32 + srow) * 1024 + kt + schunk * 8,
            &Bs[s][jj * 2048 + w * 512]);
  };

  stage(0, 0);
  stage(64, 1);
  asm volatile("s_waitcnt vmcnt(8)" ::: "memory");
  __builtin_amdgcn_sched_barrier(0);
  asm volatile("s_barrier" ::: "memory");

  for (int t = 0; t < 16; t++) {
    const int s = t & 1;
    const short* Ac = &As[s][0];
    const short* Bc = &Bs[s][0];
#pragma unroll
    for (int kk = 0; kk < 2; kk++) {
      s8v a[4], b[4];
#pragma unroll
      for (int mi = 0; mi < 4; mi++) {
        const int r_ = wm + mi * 16 + lq;
        a[mi] = *(const s8v*)&Ac[r_ * 64 + (((kk * 4 + g) ^ (lq & 7)) * 8)];
      }
#pragma unroll
      for (int ni = 0; ni < 4; ni++) {
        const int r_ = wn + ni * 16 + lq;
        b[ni] = *(const s8v*)&Bc[r_ * 64 + (((kk * 4 + g) ^ (lq & 7)) * 8)];
      }
      __builtin_amdgcn_s_setprio(1);
#pragma unroll
      for (int mi = 0; mi < 4; mi++)
#pragma unroll
        for (int ni = 0; ni < 4; ni++)
          acc[mi][ni] = __builtin_amdgcn_mfma_f32_16x16x32_bf16(a[mi], b[ni], acc[mi][ni], 0, 0, 0);
      __builtin_amdgcn_s_setprio(0);
    }
    if (t < 15) {
      asm volatile("s_waitcnt lgkmcnt(0)" ::: "memory");
      asm volatile("s_barrier" ::: "memory");
      if (t < 14) {
        stage((t + 2) * 64, s);
        asm volatile("s_waitcnt vmcnt(8)" ::: "memory");
      } else {
        asm volatile("s_waitcnt vmcnt(0)" ::: "memory");
      }
      __builtin_amdgcn_sched_barrier(0);
      asm volatile("s_barrier" ::: "memory");
    }
  }

#pragma unroll
  for (int mi = 0; mi < 4; mi++)
#pragma unroll
    for (int ni = 0; ni < 4; ni++) {
      const int o = row_n + wn + ni * 16 + lq;
#pragma unroll
      for (int r = 0; r < 4; r++) {
        const int tt = row_m + wm + mi * 16 + g * 4 + r;
        out[(size_t)tt * 1024 + o] = acc[mi][ni][r];
      }
    }
}

extern "C" void kernel_launch(void* const* d_in, const int* in_sizes, int n_in,
                              void* d_out, int out_size, void* d_ws, size_t ws_size,
                              hipStream_t stream) {
  const float* x  = (const float*)d_in[0];
  const int*   sl = (const int*)d_in[1];
  const float* wq = (const float*)d_in[2];
  const float* wk = (const float*)d_in[3];
  const float* wv = (const float*)d_in[4];
  const float* wo = (const float*)d_in[5];
  float* out = (float*)d_out;

  char* ws = (char*)d_ws;
  float* ct   = (float*)(ws + 0);          //   262144 B
  float* st   = (float*)(ws + 262144);     //   262144 B
  short* xb   = (short*)(ws + 524288);     // 16777216 B  [8192][1024]
  short* wqkv = (short*)(ws + 17301504);   //  6291456 B  [3072][1024]
  short* wob  = (short*)(ws + 23592960);   //  2097152 B  [1024][1024]
  short* qb   = (short*)(ws + 25690112);   // 16777216 B  [4][16][2048][64]
  short* kbf  = (short*)(ws + 42467328);   // 16777216 B
  short* vtb  = (short*)(ws + 76021760);   // 16777216 B  [4][16][64][2048]
  short* ab   = (short*)(ws + 92798976);   // 16777216 B  [8192][1024]
  // total 109,576,192 B

  k_prep<<<12544, 256, 0, stream>>>(x, wq, wk, wv, wo, ct, st, xb, wqkv, wob);
  k_gemm_qkv<<<1536, 256, 0, stream>>>(xb, wqkv, ct, st, qb, kbf, vtb);
  k_attn<<<512, 256, 0, stream>>>(qb, kbf, vtb, sl, ab);
  k_gemm_out<<<512, 256, 0, stream>>>(ab, wob, out);
}